// Round 11
// baseline (251.399 us; speedup 1.0000x reference)
//
#include <hip/hip_runtime.h>
#include <hip/hip_bf16.h>
#include <stdint.h>

#define NODES 50000
#define EDGES 800000
#define DIM 256
#define NREL 8
#define NJ (NREL * DIM)  // 2048 combined output cols (r*256+o)

typedef unsigned short u16;
typedef __attribute__((ext_vector_type(8))) __bf16 bf16x8;
typedef __attribute__((ext_vector_type(8))) unsigned short us8;
typedef __attribute__((ext_vector_type(4))) float f32x4;

#define GLOBAL_AS __attribute__((address_space(1)))
#define LDS_AS __attribute__((address_space(3)))

#define HIST_BLKS 3125   // 3125*256 == 800000 exactly
#define CVT_N4 (NODES * DIM / 4 + NREL * DIM * DIM / 4)  // 3,331,072
#define CVT_BLKS 13012
#define GEMM_BLKS 3200   // 8 XCD bands x (25 m-tiles x 16 j-tiles)

__device__ __forceinline__ u16 f2bf(float f) {
  uint32_t u = __builtin_bit_cast(uint32_t, f);
  u += 0x7FFFu + ((u >> 16) & 1u);  // RNE; inputs finite
  return (u16)(u >> 16);
}
__device__ __forceinline__ float bf2f(u16 u) {
  uint32_t t = (uint32_t)u << 16;
  return __builtin_bit_cast(float, t);
}

// ---------------- Tier A ----------------

// Fused: dst-histogram (blocks 0..3124) || f32->bf16 convert of x,w (rest).
// Safe fusion: both sides are LDS-free streaming kernels (r10 lesson: do NOT
// fuse random-atomic work into the LDS-heavy GEMM grid — MfmaUtil 27->15%).
__global__ __launch_bounds__(256) void k_prep(
    const float* __restrict__ x, const float* __restrict__ w,
    u16* __restrict__ xb, u16* __restrict__ wb,
    const int* __restrict__ edst, int* __restrict__ cnt)
{
  const int b = blockIdx.x;
  if (b < HIST_BLKS) {
    const int e = b * 256 + threadIdx.x;  // exact coverage of EDGES
    atomicAdd(&cnt[edst[e]], 1);
    return;
  }
  const int i = (b - HIST_BLKS) * 256 + threadIdx.x;
  const int n4x = NODES * DIM / 4;
  if (i < n4x) {
    float4 v = ((const float4*)x)[i];
    ushort4 o;
    o.x = f2bf(v.x); o.y = f2bf(v.y); o.z = f2bf(v.z); o.w = f2bf(v.w);
    ((ushort4*)xb)[i] = o;
  } else if (i < CVT_N4) {
    const int j = i - n4x;
    float4 v = ((const float4*)w)[j];
    ushort4 o;
    o.x = f2bf(v.x); o.y = f2bf(v.y); o.z = f2bf(v.z); o.w = f2bf(v.w);
    ((ushort4*)wb)[j] = o;
  }
}

// Dense GEMM h = xb @ wb^T (r9 structure, standalone again).
// BM=256 x BN=128, 512 thr / 8 waves (4x2 of 64x64), T1 XCD bands (25 m-tiles
// each), T4 counted-vmcnt 3-buffer pipeline, XOR-swizzled staging (both-sides),
// LDS-transpose coalesced epilogue.
__global__ __launch_bounds__(512) void k_gemm(
    const u16* __restrict__ xb, const u16* __restrict__ wb, u16* __restrict__ h)
{
  __shared__ __align__(16) u16 smem[36864];  // 3 x [A 8192 | B 4096] u16

  const int gbid = blockIdx.x;
  const int xcd = gbid & 7;
  const int idx = gbid >> 3;         // 0..399
  const int jg  = idx / 200;         // 0,1
  const int r2  = idx - jg * 200;
  const int m   = xcd * 25 + (r2 >> 3);
  const int mbase = m * 256;
  if (mbase >= NODES) return;
  const int jbase = (jg * 8 + (r2 & 7)) * 128;

  const int tid = threadIdx.x;
  const int lane = tid & 63;
  const int wv = tid >> 6;           // 0..7
  const int wr = wv >> 1, wc = wv & 1;
  const int swz = (lane & 3) ^ ((lane >> 2) & 3) ^ (lane >> 4);  // 16B-chunk idx

  f32x4 acc[4][4];
#pragma unroll
  for (int mm = 0; mm < 4; ++mm)
#pragma unroll
    for (int n = 0; n < 4; ++n) acc[mm][n] = f32x4{0.f, 0.f, 0.f, 0.f};

  const int arow0 = wv * 32;  // this wave stages A rows [arow0, arow0+32)
  const int brow0 = wv * 16;  // and B rows [brow0, brow0+16)

  auto STAGE = [&](int buf, int ks) {
    u16* sa = smem + buf * 12288;
    u16* sb = sa + 8192;
#pragma unroll
    for (int c2 = 0; c2 < 2; ++c2) {
      const int rowb = arow0 + c2 * 16;
      const int row  = rowb + (lane >> 2);
      const int ar = min(mbase + row, NODES - 1);  // clamp last tile
      const u16* ga = xb + ((size_t)ar << 8) + (ks << 5) + (swz << 3);
      __builtin_amdgcn_global_load_lds((const GLOBAL_AS uint32_t*)ga,
                                       (LDS_AS uint32_t*)(sa + rowb * 32), 16, 0, 0);
    }
    const int brow = brow0 + (lane >> 2);
    const u16* gb = wb + ((size_t)(jbase + brow) << 8) + (ks << 5) + (swz << 3);
    __builtin_amdgcn_global_load_lds((const GLOBAL_AS uint32_t*)gb,
                                     (LDS_AS uint32_t*)(sb + brow0 * 32), 16, 0, 0);
  };

  STAGE(0, 0);  // 3 loads in flight
#pragma unroll
  for (int ks = 0; ks < 8; ++ks) {
    if (ks < 7) {
      STAGE((ks + 1) % 3, ks + 1);                       // +3 loads (6 in flight)
      asm volatile("s_waitcnt vmcnt(3)" ::: "memory");   // prev stage landed
    } else {
      asm volatile("s_waitcnt vmcnt(0)" ::: "memory");   // final stage landed
    }
    __builtin_amdgcn_s_barrier();                        // no vmcnt(0) drain here

    const u16* sa = smem + (ks % 3) * 12288;
    const u16* sb = sa + 8192;
    bf16x8 af[4], bfr[4];
#pragma unroll
    for (int mm = 0; mm < 4; ++mm)
      af[mm] = *(const bf16x8*)(sa + (wr * 64 + mm * 16 + (lane & 15)) * 32 + swz * 8);
#pragma unroll
    for (int n = 0; n < 4; ++n)
      bfr[n] = *(const bf16x8*)(sb + (wc * 64 + n * 16 + (lane & 15)) * 32 + swz * 8);
#pragma unroll
    for (int mm = 0; mm < 4; ++mm)
#pragma unroll
      for (int n = 0; n < 4; ++n)
        acc[mm][n] = __builtin_amdgcn_mfma_f32_16x16x32_bf16(af[mm], bfr[n], acc[mm][n], 0, 0, 0);
  }
  __syncthreads();  // all waves done reading bufs before tile overwrite

  // Epilogue: acc -> 256x128 LDS tile (XOR key: simultaneous rows hit disjoint
  // bank quartets), then coalesced 16B stores.
  u16* tile = smem;  // 256x128 u16 = 64KB
#pragma unroll
  for (int mm = 0; mm < 4; ++mm) {
#pragma unroll
    for (int q = 0; q < 4; ++q) {
      const int rt = wr * 64 + mm * 16 + (lane >> 4) * 4 + q;
      const int key = ((rt >> 2) & 3) << 4;
#pragma unroll
      for (int n = 0; n < 4; ++n) {
        const int ct = wc * 64 + n * 16 + (lane & 15);
        tile[rt * 128 + (ct ^ key)] = f2bf(acc[mm][n][q]);
      }
    }
  }
  __syncthreads();
#pragma unroll
  for (int i = 0; i < 8; ++i) {
    const int c = tid + i * 512;
    const int row = c >> 4, chunk = c & 15;
    const int grow = mbase + row;
    if (grow < NODES) {
      const int key = ((row >> 2) & 3) << 4;
      const us8 v = *(const us8*)(tile + row * 128 + ((chunk * 8) ^ key));
      *((us8*)(h + (size_t)grow * NJ + jbase) + chunk) = v;
    }
  }
}

// ---- scan chain (3 small multi-block kernels; r5: never single-block) ----
#define SCAN_BLOCKS 196  // ceil(50000/256)

__global__ void k_bsum(const int* __restrict__ cnt, int* __restrict__ bs) {
  int i = blockIdx.x * blockDim.x + threadIdx.x;
  int v = (i < NODES) ? cnt[i] : 0;
#pragma unroll
  for (int o = 32; o; o >>= 1) v += __shfl_down(v, o);
  __shared__ int wsum[4];
  if ((threadIdx.x & 63) == 0) wsum[threadIdx.x >> 6] = v;
  __syncthreads();
  if (threadIdx.x == 0) bs[blockIdx.x] = wsum[0] + wsum[1] + wsum[2] + wsum[3];
}
__global__ void k_bscan(int* __restrict__ bs) {  // exclusive scan of SCAN_BLOCKS, 1 block
  __shared__ int tmp[SCAN_BLOCKS];
  int t = threadIdx.x;
  if (t < SCAN_BLOCKS) tmp[t] = bs[t];
  __syncthreads();
  if (t == 0) {
    int s = 0;
    for (int i = 0; i < SCAN_BLOCKS; ++i) { int c = tmp[i]; tmp[i] = s; s += c; }
  }
  __syncthreads();
  if (t < SCAN_BLOCKS) bs[t] = tmp[t];
}
__global__ void k_scan2(const int* __restrict__ cnt, const int* __restrict__ bs,
                        int* __restrict__ row_ptr, int* __restrict__ cur) {
  int t = threadIdx.x;
  int i = blockIdx.x * blockDim.x + t;
  int v = (i < NODES) ? cnt[i] : 0;
  __shared__ int tmp[256];
  tmp[t] = v;
  __syncthreads();
  for (int o = 1; o < 256; o <<= 1) {  // Hillis-Steele inclusive
    int u = (t >= o) ? tmp[t - o] : 0;
    __syncthreads();
    tmp[t] += u;
    __syncthreads();
  }
  int val = bs[blockIdx.x] + tmp[t] - v;  // exclusive
  if (i <= NODES) row_ptr[i] = val;       // row_ptr[NODES] lands on EDGES
  if (i < NODES) cur[i] = val;
}

// Standalone scatter again (LDS-free, 256-thr blocks).
__global__ __launch_bounds__(256) void k_scatter2(
    const int* __restrict__ esrc, const int* __restrict__ edst,
    const int* __restrict__ et, int* __restrict__ cur, int* __restrict__ sg)
{
  const int e = blockIdx.x * 256 + threadIdx.x;  // exact coverage
  const int p = atomicAdd(&cur[edst[e]], 1);     // in-bin order irrelevant
  sg[p] = esrc[e] * NREL + et[e];                // h row index
}

// Two dst nodes per wave (32 lanes x ushort8 = 512B row): 4-deep gather ILP
// per half-wave, 25K waves of TLP.
__global__ __launch_bounds__(256) void k_reduce(
    const u16* __restrict__ h, const int* __restrict__ row_ptr,
    const int* __restrict__ sg, const float* __restrict__ bias,
    float* __restrict__ out)
{
  const int gw = (int)((blockIdx.x * blockDim.x + threadIdx.x) >> 6);
  const int node = gw * 2 + ((threadIdx.x >> 5) & 1);
  if (node >= NODES) return;
  const int l = threadIdx.x & 31;
  const int lo = row_ptr[node], hi = row_ptr[node + 1];
  const u16* hb = h + l * 8;

  float a[8] = {0.f, 0.f, 0.f, 0.f, 0.f, 0.f, 0.f, 0.f};
  int e = lo;
  for (; e + 4 <= hi; e += 4) {  // 4 x 512B gathers in flight per half-wave
    const us8 v0 = *(const us8*)(hb + ((size_t)sg[e] << 8));
    const us8 v1 = *(const us8*)(hb + ((size_t)sg[e + 1] << 8));
    const us8 v2 = *(const us8*)(hb + ((size_t)sg[e + 2] << 8));
    const us8 v3 = *(const us8*)(hb + ((size_t)sg[e + 3] << 8));
#pragma unroll
    for (int j = 0; j < 8; ++j)
      a[j] += (bf2f(v0[j]) + bf2f(v1[j])) + (bf2f(v2[j]) + bf2f(v3[j]));
  }
  for (; e < hi; ++e) {
    const us8 v = *(const us8*)(hb + ((size_t)sg[e] << 8));
#pragma unroll
    for (int j = 0; j < 8; ++j) a[j] += bf2f(v[j]);
  }
  const float4 b0 = ((const float4*)bias)[l * 2];
  const float4 b1 = ((const float4*)bias)[l * 2 + 1];
  f32x4 o0 = {a[0] + b0.x, a[1] + b0.y, a[2] + b0.z, a[3] + b0.w};
  f32x4 o1 = {a[4] + b1.x, a[5] + b1.y, a[6] + b1.z, a[7] + b1.w};
  f32x4* op = (f32x4*)(out + (size_t)node * DIM) + l * 2;
  __builtin_nontemporal_store(o0, op);
  __builtin_nontemporal_store(o1, op + 1);
}

// ---------------- Tier B: round-2 path (per-relation gathered GEMM + atomics) ----------------

__global__ void k_init_out(float* __restrict__ out, const float* __restrict__ bias) {
  int i = blockIdx.x * blockDim.x + threadIdx.x;
  ((float4*)out)[i] = ((const float4*)bias)[i & 63];
}
__global__ void k_cvt(const float* __restrict__ in, u16* __restrict__ outp, int n4) {
  int i = blockIdx.x * blockDim.x + threadIdx.x;
  if (i >= n4) return;
  float4 v = ((const float4*)in)[i];
  ushort4 o;
  o.x = f2bf(v.x); o.y = f2bf(v.y); o.z = f2bf(v.z); o.w = f2bf(v.w);
  ((ushort4*)outp)[i] = o;
}
__global__ void k_zero8(int* __restrict__ meta) {
  if (threadIdx.x < 8) meta[threadIdx.x] = 0;
}
#define SORT_BLOCKS 256
#define SORT_CHUNK ((EDGES + SORT_BLOCKS - 1) / SORT_BLOCKS)
__global__ void k_hist(const int* __restrict__ et, int* __restrict__ meta) {
  __shared__ int lh[NREL];
  if (threadIdx.x < NREL) lh[threadIdx.x] = 0;
  __syncthreads();
  const int lo = blockIdx.x * SORT_CHUNK, hi = min(EDGES, lo + SORT_CHUNK);
  for (int e = lo + threadIdx.x; e < hi; e += blockDim.x) atomicAdd(&lh[et[e]], 1);
  __syncthreads();
  if (threadIdx.x < NREL && lh[threadIdx.x]) atomicAdd(&meta[threadIdx.x], lh[threadIdx.x]);
}
__global__ void k_scan(int* __restrict__ meta) {
  if (threadIdx.x == 0) {
    int s = 0;
    for (int r = 0; r < NREL; ++r) { meta[8 + r] = s; meta[17 + r] = s; s += meta[r]; }
    meta[16] = s;
  }
}
__global__ void k_scatter(const int* __restrict__ et, int* __restrict__ meta,
                          int* __restrict__ perm) {
  __shared__ int lh[NREL];
  __shared__ int lc[NREL];
  if (threadIdx.x < NREL) lh[threadIdx.x] = 0;
  __syncthreads();
  const int lo = blockIdx.x * SORT_CHUNK, hi = min(EDGES, lo + SORT_CHUNK);
  for (int e = lo + threadIdx.x; e < hi; e += blockDim.x) atomicAdd(&lh[et[e]], 1);
  __syncthreads();
  if (threadIdx.x < NREL) {
    const int c = lh[threadIdx.x];
    lc[threadIdx.x] = c ? atomicAdd(&meta[17 + threadIdx.x], c) : 0;
  }
  __syncthreads();
  for (int e = lo + threadIdx.x; e < hi; e += blockDim.x) {
    const int p = atomicAdd(&lc[et[e]], 1);
    perm[p] = e;
  }
}
__global__ __launch_bounds__(256) void k_gemm_b(
    const u16* __restrict__ xb, const u16* __restrict__ wb,
    const int* __restrict__ perm, const int* __restrict__ meta,
    const int* __restrict__ esrc, const int* __restrict__ edst,
    float* __restrict__ out)
{
  const int r = blockIdx.z;
  const int estart = meta[8 + r], eend = meta[9 + r];
  const int base = estart + (int)blockIdx.x * 128;
  if (base >= eend) return;
  const int mcount = min(128, eend - base);
  const int ny = blockIdx.y;
  __shared__ int s_src[128];
  __shared__ int s_dst[128];
  __shared__ __align__(16) u16 s_a[128 * 32];
  __shared__ __align__(16) u16 s_b[128 * 32];
  const int tid = threadIdx.x;
  if (tid < 128) {
    int sv = 0, dv = 0;
    if (tid < mcount) { int e = perm[base + tid]; sv = esrc[e]; dv = edst[e]; }
    s_src[tid] = sv; s_dst[tid] = dv;
  }
  __syncthreads();
  const int lane = tid & 63;
  const int wv = tid >> 6;
  const int wr = wv >> 1, wc = wv & 1;
  const int swz = (lane & 3) ^ ((lane >> 2) & 3) ^ (lane >> 4);
  f32x4 acc[4][4];
#pragma unroll
  for (int m = 0; m < 4; ++m)
#pragma unroll
    for (int n = 0; n < 4; ++n) acc[m][n] = f32x4{0.f, 0.f, 0.f, 0.f};
  const int arow0 = wv * 32;
  const size_t wbase = ((size_t)r << 16) + ((size_t)ny << 15);
  for (int ks = 0; ks < 8; ++ks) {
#pragma unroll
    for (int c2 = 0; c2 < 2; ++c2) {
      const int rowb = arow0 + c2 * 16;
      const int row  = rowb + (lane >> 2);
      const u16* ga = xb + ((size_t)s_src[row] << 8) + (ks << 5) + (swz << 3);
      __builtin_amdgcn_global_load_lds((const GLOBAL_AS uint32_t*)ga,
                                       (LDS_AS uint32_t*)(s_a + rowb * 32), 16, 0, 0);
      const u16* gb = wb + wbase + ((size_t)row << 8) + (ks << 5) + (swz << 3);
      __builtin_amdgcn_global_load_lds((const GLOBAL_AS uint32_t*)gb,
                                       (LDS_AS uint32_t*)(s_b + rowb * 32), 16, 0, 0);
    }
    __syncthreads();
    bf16x8 af[4], bfr[4];
#pragma unroll
    for (int m = 0; m < 4; ++m)
      af[m] = *(const bf16x8*)(s_a + (wr * 64 + m * 16 + (lane & 15)) * 32 + swz * 8);
#pragma unroll
    for (int n = 0; n < 4; ++n)
      bfr[n] = *(const bf16x8*)(s_b + (wc * 64 + n * 16 + (lane & 15)) * 32 + swz * 8);
#pragma unroll
    for (int m = 0; m < 4; ++m)
#pragma unroll
      for (int n = 0; n < 4; ++n)
        acc[m][n] = __builtin_amdgcn_mfma_f32_16x16x32_bf16(af[m], bfr[n], acc[m][n], 0, 0, 0);
    __syncthreads();
  }
  const int colb = ny * 128 + wc * 64 + (lane & 15);
#pragma unroll
  for (int m = 0; m < 4; ++m) {
#pragma unroll
    for (int q = 0; q < 4; ++q) {
      const int rl = wr * 64 + m * 16 + (lane >> 4) * 4 + q;
      if (rl < mcount) {
        float* op = out + (size_t)s_dst[rl] * DIM + colb;
#pragma unroll
        for (int n = 0; n < 4; ++n) atomicAdd(op + n * 16, acc[m][n][q]);
      }
    }
  }
}

// Tier C: correctness-only fallback.
__global__ void k_naive(const float* __restrict__ x, const float* __restrict__ w,
                        const int* __restrict__ esrc, const int* __restrict__ edst,
                        const int* __restrict__ et, float* __restrict__ out)
{
  const int lane = threadIdx.x & 63;
  int gw = (blockIdx.x * blockDim.x + threadIdx.x) >> 6;
  const int nw = (gridDim.x * blockDim.x) >> 6;
  for (int e = gw; e < EDGES; e += nw) {
    const int s = esrc[e], d = edst[e], r = et[e];
    const float* xr = x + (size_t)s * DIM;
    const float* wr0 = w + (size_t)r * DIM * DIM;
    float a[4] = {0.f, 0.f, 0.f, 0.f};
    for (int i = 0; i < DIM; ++i) {
      const float xv = xr[i];
#pragma unroll
      for (int c = 0; c < 4; ++c) a[c] += xv * wr0[(size_t)(lane + c * 64) * DIM + i];
    }
#pragma unroll
    for (int c = 0; c < 4; ++c) atomicAdd(&out[(size_t)d * DIM + lane + c * 64], a[c]);
  }
}

extern "C" void kernel_launch(void* const* d_in, const int* in_sizes, int n_in,
                              void* d_out, int out_size, void* d_ws, size_t ws_size,
                              hipStream_t stream) {
  const float* x    = (const float*)d_in[0];
  const float* w    = (const float*)d_in[1];
  const float* bias = (const float*)d_in[2];
  const int* eidx   = (const int*)d_in[3];
  const int* et     = (const int*)d_in[4];
  const int* esrc = eidx;
  const int* edst = eidx + EDGES;
  float* out = (float*)d_out;

  auto pad = [](size_t v) { return (v + 255) & ~(size_t)255; };

  // Tier A layout
  size_t needA = 0;
  const size_t a_xb = needA;  needA = pad(needA + (size_t)NODES * DIM * 2);
  const size_t a_wb = needA;  needA = pad(needA + (size_t)NREL * DIM * DIM * 2);
  const size_t a_h  = needA;  needA = pad(needA + (size_t)NODES * NJ * 2);
  const size_t a_cnt = needA; needA = pad(needA + (size_t)NODES * 4);
  const size_t a_rp  = needA; needA = pad(needA + ((size_t)NODES + 1) * 4);
  const size_t a_cur = needA; needA = pad(needA + (size_t)NODES * 4);
  const size_t a_bs  = needA; needA = pad(needA + (size_t)SCAN_BLOCKS * 4);
  const size_t a_sg  = needA; needA = pad(needA + (size_t)EDGES * 4);

  // Tier B layout
  size_t needB = 0;
  const size_t b_xb = needB;   needB = pad(needB + (size_t)NODES * DIM * 2);
  const size_t b_wb = needB;   needB = pad(needB + (size_t)NREL * DIM * DIM * 2);
  const size_t b_perm = needB; needB = pad(needB + (size_t)EDGES * 4);
  const size_t b_meta = needB; needB = pad(needB + 64 * 4);

  char* ws = (char*)d_ws;
  if (needA <= ws_size) {
    u16* xb = (u16*)(ws + a_xb);
    u16* wb = (u16*)(ws + a_wb);
    u16* h  = (u16*)(ws + a_h);
    int* cnt = (int*)(ws + a_cnt);
    int* rp  = (int*)(ws + a_rp);
    int* cur = (int*)(ws + a_cur);
    int* bs  = (int*)(ws + a_bs);
    int* sg  = (int*)(ws + a_sg);

    (void)hipMemsetAsync(cnt, 0, (size_t)NODES * 4, stream);
    k_prep<<<HIST_BLKS + CVT_BLKS, 256, 0, stream>>>(x, w, xb, wb, edst, cnt);
    k_bsum<<<SCAN_BLOCKS, 256, 0, stream>>>(cnt, bs);
    k_bscan<<<1, 256, 0, stream>>>(bs);
    k_scan2<<<SCAN_BLOCKS, 256, 0, stream>>>(cnt, bs, rp, cur);
    k_scatter2<<<HIST_BLKS, 256, 0, stream>>>(esrc, edst, et, cur, sg);
    k_gemm<<<GEMM_BLKS, 512, 0, stream>>>(xb, wb, h);
    k_reduce<<<(NODES / 2 * 64 + 255) / 256, 256, 0, stream>>>(h, rp, sg, bias, out);
  } else if (needB <= ws_size) {
    u16* xb  = (u16*)(ws + b_xb);
    u16* wbb = (u16*)(ws + b_wb);
    int* perm = (int*)(ws + b_perm);
    int* meta = (int*)(ws + b_meta);
    k_init_out<<<12500, 256, 0, stream>>>(out, bias);
    k_cvt<<<12500, 256, 0, stream>>>(x, xb, NODES * DIM / 4);
    k_cvt<<<512, 256, 0, stream>>>(w, wbb, NREL * DIM * DIM / 4);
    k_zero8<<<1, 64, 0, stream>>>(meta);
    k_hist<<<SORT_BLOCKS, 256, 0, stream>>>(et, meta);
    k_scan<<<1, 1, 0, stream>>>(meta);
    k_scatter<<<SORT_BLOCKS, 256, 0, stream>>>(et, meta, perm);
    dim3 g(6250, 2, NREL);
    k_gemm_b<<<g, 256, 0, stream>>>(xb, wbb, perm, meta, esrc, edst, out);
  } else {
    k_init_out<<<12500, 256, 0, stream>>>(out, bias);
    k_naive<<<2048, 256, 0, stream>>>(x, w, esrc, edst, et, out);
  }
}

// Round 12
// 201.253 us; speedup vs baseline: 1.2492x; 1.2492x over previous
//
#include <hip/hip_runtime.h>
#include <hip/hip_bf16.h>
#include <stdint.h>

#define NODES 50000
#define EDGES 800000
#define DIM 256
#define NREL 8
#define NJ (NREL * DIM)  // 2048 combined output cols (r*256+o)
#define CAP 64           // padded-CSR slots per node (Poisson(16): P(deg>=64)~2e-18)

typedef unsigned short u16;
typedef __attribute__((ext_vector_type(8))) __bf16 bf16x8;
typedef __attribute__((ext_vector_type(8))) unsigned short us8;
typedef __attribute__((ext_vector_type(4))) float f32x4;

#define GLOBAL_AS __attribute__((address_space(1)))
#define LDS_AS __attribute__((address_space(3)))

#define ZERO_BLKS 49     // 50000 ints as 12500 int4 -> 49*256=12544 threads
#define CVT_N4 (NODES * DIM / 4 + NREL * DIM * DIM / 4)  // 3,331,072 = 13012*256
#define CVT_BLKS 13012
#define EDGE_BLKS 3125   // 3125*256 == 800000 exactly
#define GEMM_BLKS 3200   // 8 XCD bands x (25 m-tiles x 16 j-tiles)

__device__ __forceinline__ u16 f2bf(float f) {
  uint32_t u = __builtin_bit_cast(uint32_t, f);
  u += 0x7FFFu + ((u >> 16) & 1u);  // RNE; inputs finite
  return (u16)(u >> 16);
}
__device__ __forceinline__ float bf2f(u16 u) {
  uint32_t t = (uint32_t)u << 16;
  return __builtin_bit_cast(float, t);
}

// ---------------- Tier A (padded CSR: no hist/scan kernels at all) ----------------

// Fused: zero cnt (blocks 0..48, int4) || f32->bf16 convert of x,w (rest).
__global__ __launch_bounds__(256) void k_prep_pad(
    const float* __restrict__ x, const float* __restrict__ w,
    u16* __restrict__ xb, u16* __restrict__ wb, int* __restrict__ cnt)
{
  const int b = blockIdx.x;
  if (b < ZERO_BLKS) {
    const int i4 = b * 256 + threadIdx.x;
    if (i4 < (NODES + 3) / 4) ((int4*)cnt)[i4] = int4{0, 0, 0, 0};
    return;
  }
  const int i = (b - ZERO_BLKS) * 256 + threadIdx.x;
  const int n4x = NODES * DIM / 4;
  if (i < n4x) {
    float4 v = ((const float4*)x)[i];
    ushort4 o;
    o.x = f2bf(v.x); o.y = f2bf(v.y); o.z = f2bf(v.z); o.w = f2bf(v.w);
    ((ushort4*)xb)[i] = o;
  } else if (i < CVT_N4) {
    const int j = i - n4x;
    float4 v = ((const float4*)w)[j];
    ushort4 o;
    o.x = f2bf(v.x); o.y = f2bf(v.y); o.z = f2bf(v.z); o.w = f2bf(v.w);
    ((ushort4*)wb)[j] = o;
  }
}

// Single-pass bucket scatter into fixed-capacity per-node slots.
// Replaces hist+bsum+bscan+scan2+scatter (4 kernels + memset) of the exact-CSR path.
__global__ __launch_bounds__(256) void k_scatter_pad(
    const int* __restrict__ esrc, const int* __restrict__ edst,
    const int* __restrict__ et, int* __restrict__ cnt, int* __restrict__ slot)
{
  const int e = blockIdx.x * 256 + threadIdx.x;  // exact coverage of EDGES
  const int d = edst[e];
  const int p = atomicAdd(&cnt[d], 1);           // ~16-way avg contention: harmless
  if (p < CAP) slot[d * CAP + p] = esrc[e] * NREL + et[e];
}

// Dense GEMM h = xb @ wb^T (r9/r11 structure).
// BM=256 x BN=128, 512 thr / 8 waves (4x2 of 64x64), T1 XCD bands (25 m-tiles
// each), T4 counted-vmcnt 3-buffer pipeline, XOR-swizzled staging (both-sides),
// LDS-transpose coalesced epilogue.
__global__ __launch_bounds__(512) void k_gemm(
    const u16* __restrict__ xb, const u16* __restrict__ wb, u16* __restrict__ h)
{
  __shared__ __align__(16) u16 smem[36864];  // 3 x [A 8192 | B 4096] u16

  const int gbid = blockIdx.x;
  const int xcd = gbid & 7;
  const int idx = gbid >> 3;         // 0..399
  const int jg  = idx / 200;         // 0,1
  const int r2  = idx - jg * 200;
  const int m   = xcd * 25 + (r2 >> 3);
  const int mbase = m * 256;
  if (mbase >= NODES) return;
  const int jbase = (jg * 8 + (r2 & 7)) * 128;

  const int tid = threadIdx.x;
  const int lane = tid & 63;
  const int wv = tid >> 6;           // 0..7
  const int wr = wv >> 1, wc = wv & 1;
  const int swz = (lane & 3) ^ ((lane >> 2) & 3) ^ (lane >> 4);  // 16B-chunk idx

  f32x4 acc[4][4];
#pragma unroll
  for (int mm = 0; mm < 4; ++mm)
#pragma unroll
    for (int n = 0; n < 4; ++n) acc[mm][n] = f32x4{0.f, 0.f, 0.f, 0.f};

  const int arow0 = wv * 32;  // this wave stages A rows [arow0, arow0+32)
  const int brow0 = wv * 16;  // and B rows [brow0, brow0+16)

  auto STAGE = [&](int buf, int ks) {
    u16* sa = smem + buf * 12288;
    u16* sb = sa + 8192;
#pragma unroll
    for (int c2 = 0; c2 < 2; ++c2) {
      const int rowb = arow0 + c2 * 16;
      const int row  = rowb + (lane >> 2);
      const int ar = min(mbase + row, NODES - 1);  // clamp last tile
      const u16* ga = xb + ((size_t)ar << 8) + (ks << 5) + (swz << 3);
      __builtin_amdgcn_global_load_lds((const GLOBAL_AS uint32_t*)ga,
                                       (LDS_AS uint32_t*)(sa + rowb * 32), 16, 0, 0);
    }
    const int brow = brow0 + (lane >> 2);
    const u16* gb = wb + ((size_t)(jbase + brow) << 8) + (ks << 5) + (swz << 3);
    __builtin_amdgcn_global_load_lds((const GLOBAL_AS uint32_t*)gb,
                                     (LDS_AS uint32_t*)(sb + brow0 * 32), 16, 0, 0);
  };

  STAGE(0, 0);  // 3 loads in flight
#pragma unroll
  for (int ks = 0; ks < 8; ++ks) {
    if (ks < 7) {
      STAGE((ks + 1) % 3, ks + 1);                       // +3 loads (6 in flight)
      asm volatile("s_waitcnt vmcnt(3)" ::: "memory");   // prev stage landed
    } else {
      asm volatile("s_waitcnt vmcnt(0)" ::: "memory");   // final stage landed
    }
    __builtin_amdgcn_s_barrier();                        // no vmcnt(0) drain here

    const u16* sa = smem + (ks % 3) * 12288;
    const u16* sb = sa + 8192;
    bf16x8 af[4], bfr[4];
#pragma unroll
    for (int mm = 0; mm < 4; ++mm)
      af[mm] = *(const bf16x8*)(sa + (wr * 64 + mm * 16 + (lane & 15)) * 32 + swz * 8);
#pragma unroll
    for (int n = 0; n < 4; ++n)
      bfr[n] = *(const bf16x8*)(sb + (wc * 64 + n * 16 + (lane & 15)) * 32 + swz * 8);
#pragma unroll
    for (int mm = 0; mm < 4; ++mm)
#pragma unroll
      for (int n = 0; n < 4; ++n)
        acc[mm][n] = __builtin_amdgcn_mfma_f32_16x16x32_bf16(af[mm], bfr[n], acc[mm][n], 0, 0, 0);
  }
  __syncthreads();  // all waves done reading bufs before tile overwrite

  // Epilogue: acc -> 256x128 LDS tile, then coalesced 16B stores.
  u16* tile = smem;  // 256x128 u16 = 64KB
#pragma unroll
  for (int mm = 0; mm < 4; ++mm) {
#pragma unroll
    for (int q = 0; q < 4; ++q) {
      const int rt = wr * 64 + mm * 16 + (lane >> 4) * 4 + q;
      const int key = ((rt >> 2) & 3) << 4;
#pragma unroll
      for (int n = 0; n < 4; ++n) {
        const int ct = wc * 64 + n * 16 + (lane & 15);
        tile[rt * 128 + (ct ^ key)] = f2bf(acc[mm][n][q]);
      }
    }
  }
  __syncthreads();
#pragma unroll
  for (int i = 0; i < 8; ++i) {
    const int c = tid + i * 512;
    const int row = c >> 4, chunk = c & 15;
    const int grow = mbase + row;
    if (grow < NODES) {
      const int key = ((row >> 2) & 3) << 4;
      const us8 v = *(const us8*)(tile + row * 128 + ((chunk * 8) ^ key));
      *((us8*)(h + (size_t)grow * NJ + jbase) + chunk) = v;
    }
  }
}

// Two dst nodes per wave (32 lanes x ushort8 = 512B row), padded-slot edge list.
__global__ __launch_bounds__(256) void k_reduce_pad(
    const u16* __restrict__ h, const int* __restrict__ cnt,
    const int* __restrict__ slot, const float* __restrict__ bias,
    float* __restrict__ out)
{
  const int gw = (int)((blockIdx.x * blockDim.x + threadIdx.x) >> 6);
  const int node = gw * 2 + ((threadIdx.x >> 5) & 1);
  if (node >= NODES) return;
  const int l = threadIdx.x & 31;
  const int lo = node * CAP;
  const int hi = lo + min(cnt[node], CAP);
  const u16* hb = h + l * 8;

  float a[8] = {0.f, 0.f, 0.f, 0.f, 0.f, 0.f, 0.f, 0.f};
  int e = lo;
  for (; e + 4 <= hi; e += 4) {  // 4 x 512B gathers in flight per half-wave
    const us8 v0 = *(const us8*)(hb + ((size_t)slot[e] << 8));
    const us8 v1 = *(const us8*)(hb + ((size_t)slot[e + 1] << 8));
    const us8 v2 = *(const us8*)(hb + ((size_t)slot[e + 2] << 8));
    const us8 v3 = *(const us8*)(hb + ((size_t)slot[e + 3] << 8));
#pragma unroll
    for (int j = 0; j < 8; ++j)
      a[j] += (bf2f(v0[j]) + bf2f(v1[j])) + (bf2f(v2[j]) + bf2f(v3[j]));
  }
  for (; e < hi; ++e) {
    const us8 v = *(const us8*)(hb + ((size_t)slot[e] << 8));
#pragma unroll
    for (int j = 0; j < 8; ++j) a[j] += bf2f(v[j]);
  }
  const float4 b0 = ((const float4*)bias)[l * 2];
  const float4 b1 = ((const float4*)bias)[l * 2 + 1];
  f32x4 o0 = {a[0] + b0.x, a[1] + b0.y, a[2] + b0.z, a[3] + b0.w};
  f32x4 o1 = {a[4] + b1.x, a[5] + b1.y, a[6] + b1.z, a[7] + b1.w};
  f32x4* op = (f32x4*)(out + (size_t)node * DIM) + l * 2;
  __builtin_nontemporal_store(o0, op);
  __builtin_nontemporal_store(o1, op + 1);
}

// ---------------- Tier A2: exact-CSR path (r11) if ws too small for slots ----------------

#define HIST_BLKS 3125
__global__ __launch_bounds__(256) void k_prep(
    const float* __restrict__ x, const float* __restrict__ w,
    u16* __restrict__ xb, u16* __restrict__ wb,
    const int* __restrict__ edst, int* __restrict__ cnt)
{
  const int b = blockIdx.x;
  if (b < HIST_BLKS) {
    const int e = b * 256 + threadIdx.x;
    atomicAdd(&cnt[edst[e]], 1);
    return;
  }
  const int i = (b - HIST_BLKS) * 256 + threadIdx.x;
  const int n4x = NODES * DIM / 4;
  if (i < n4x) {
    float4 v = ((const float4*)x)[i];
    ushort4 o;
    o.x = f2bf(v.x); o.y = f2bf(v.y); o.z = f2bf(v.z); o.w = f2bf(v.w);
    ((ushort4*)xb)[i] = o;
  } else if (i < CVT_N4) {
    const int j = i - n4x;
    float4 v = ((const float4*)w)[j];
    ushort4 o;
    o.x = f2bf(v.x); o.y = f2bf(v.y); o.z = f2bf(v.z); o.w = f2bf(v.w);
    ((ushort4*)wb)[j] = o;
  }
}
#define SCAN_BLOCKS 196
__global__ void k_bsum(const int* __restrict__ cnt, int* __restrict__ bs) {
  int i = blockIdx.x * blockDim.x + threadIdx.x;
  int v = (i < NODES) ? cnt[i] : 0;
#pragma unroll
  for (int o = 32; o; o >>= 1) v += __shfl_down(v, o);
  __shared__ int wsum[4];
  if ((threadIdx.x & 63) == 0) wsum[threadIdx.x >> 6] = v;
  __syncthreads();
  if (threadIdx.x == 0) bs[blockIdx.x] = wsum[0] + wsum[1] + wsum[2] + wsum[3];
}
__global__ void k_bscan(int* __restrict__ bs) {
  __shared__ int tmp[SCAN_BLOCKS];
  int t = threadIdx.x;
  if (t < SCAN_BLOCKS) tmp[t] = bs[t];
  __syncthreads();
  if (t == 0) {
    int s = 0;
    for (int i = 0; i < SCAN_BLOCKS; ++i) { int c = tmp[i]; tmp[i] = s; s += c; }
  }
  __syncthreads();
  if (t < SCAN_BLOCKS) bs[t] = tmp[t];
}
__global__ void k_scan2(const int* __restrict__ cnt, const int* __restrict__ bs,
                        int* __restrict__ row_ptr, int* __restrict__ cur) {
  int t = threadIdx.x;
  int i = blockIdx.x * blockDim.x + t;
  int v = (i < NODES) ? cnt[i] : 0;
  __shared__ int tmp[256];
  tmp[t] = v;
  __syncthreads();
  for (int o = 1; o < 256; o <<= 1) {
    int u = (t >= o) ? tmp[t - o] : 0;
    __syncthreads();
    tmp[t] += u;
    __syncthreads();
  }
  int val = bs[blockIdx.x] + tmp[t] - v;
  if (i <= NODES) row_ptr[i] = val;
  if (i < NODES) cur[i] = val;
}
__global__ __launch_bounds__(256) void k_scatter2(
    const int* __restrict__ esrc, const int* __restrict__ edst,
    const int* __restrict__ et, int* __restrict__ cur, int* __restrict__ sg)
{
  const int e = blockIdx.x * 256 + threadIdx.x;
  const int p = atomicAdd(&cur[edst[e]], 1);
  sg[p] = esrc[e] * NREL + et[e];
}
__global__ __launch_bounds__(256) void k_reduce_csr(
    const u16* __restrict__ h, const int* __restrict__ row_ptr,
    const int* __restrict__ sg, const float* __restrict__ bias,
    float* __restrict__ out)
{
  const int gw = (int)((blockIdx.x * blockDim.x + threadIdx.x) >> 6);
  const int node = gw * 2 + ((threadIdx.x >> 5) & 1);
  if (node >= NODES) return;
  const int l = threadIdx.x & 31;
  const int lo = row_ptr[node], hi = row_ptr[node + 1];
  const u16* hb = h + l * 8;
  float a[8] = {0.f, 0.f, 0.f, 0.f, 0.f, 0.f, 0.f, 0.f};
  int e = lo;
  for (; e + 4 <= hi; e += 4) {
    const us8 v0 = *(const us8*)(hb + ((size_t)sg[e] << 8));
    const us8 v1 = *(const us8*)(hb + ((size_t)sg[e + 1] << 8));
    const us8 v2 = *(const us8*)(hb + ((size_t)sg[e + 2] << 8));
    const us8 v3 = *(const us8*)(hb + ((size_t)sg[e + 3] << 8));
#pragma unroll
    for (int j = 0; j < 8; ++j)
      a[j] += (bf2f(v0[j]) + bf2f(v1[j])) + (bf2f(v2[j]) + bf2f(v3[j]));
  }
  for (; e < hi; ++e) {
    const us8 v = *(const us8*)(hb + ((size_t)sg[e] << 8));
#pragma unroll
    for (int j = 0; j < 8; ++j) a[j] += bf2f(v[j]);
  }
  const float4 b0 = ((const float4*)bias)[l * 2];
  const float4 b1 = ((const float4*)bias)[l * 2 + 1];
  f32x4 o0 = {a[0] + b0.x, a[1] + b0.y, a[2] + b0.z, a[3] + b0.w};
  f32x4 o1 = {a[4] + b1.x, a[5] + b1.y, a[6] + b1.z, a[7] + b1.w};
  f32x4* op = (f32x4*)(out + (size_t)node * DIM) + l * 2;
  __builtin_nontemporal_store(o0, op);
  __builtin_nontemporal_store(o1, op + 1);
}

// ---------------- Tier B / C fallbacks ----------------

__global__ void k_init_out(float* __restrict__ out, const float* __restrict__ bias) {
  int i = blockIdx.x * blockDim.x + threadIdx.x;
  ((float4*)out)[i] = ((const float4*)bias)[i & 63];
}
__global__ void k_naive(const float* __restrict__ x, const float* __restrict__ w,
                        const int* __restrict__ esrc, const int* __restrict__ edst,
                        const int* __restrict__ et, float* __restrict__ out)
{
  const int lane = threadIdx.x & 63;
  int gw = (blockIdx.x * blockDim.x + threadIdx.x) >> 6;
  const int nw = (gridDim.x * blockDim.x) >> 6;
  for (int e = gw; e < EDGES; e += nw) {
    const int s = esrc[e], d = edst[e], r = et[e];
    const float* xr = x + (size_t)s * DIM;
    const float* wr0 = w + (size_t)r * DIM * DIM;
    float a[4] = {0.f, 0.f, 0.f, 0.f};
    for (int i = 0; i < DIM; ++i) {
      const float xv = xr[i];
#pragma unroll
      for (int c = 0; c < 4; ++c) a[c] += xv * wr0[(size_t)(lane + c * 64) * DIM + i];
    }
#pragma unroll
    for (int c = 0; c < 4; ++c) atomicAdd(&out[(size_t)d * DIM + lane + c * 64], a[c]);
  }
}

extern "C" void kernel_launch(void* const* d_in, const int* in_sizes, int n_in,
                              void* d_out, int out_size, void* d_ws, size_t ws_size,
                              hipStream_t stream) {
  const float* x    = (const float*)d_in[0];
  const float* w    = (const float*)d_in[1];
  const float* bias = (const float*)d_in[2];
  const int* eidx   = (const int*)d_in[3];
  const int* et     = (const int*)d_in[4];
  const int* esrc = eidx;
  const int* edst = eidx + EDGES;
  float* out = (float*)d_out;

  auto pad = [](size_t v) { return (v + 255) & ~(size_t)255; };

  // Tier A (padded CSR)
  size_t needA = 0;
  const size_t a_xb = needA;   needA = pad(needA + (size_t)NODES * DIM * 2);
  const size_t a_wb = needA;   needA = pad(needA + (size_t)NREL * DIM * DIM * 2);
  const size_t a_h  = needA;   needA = pad(needA + (size_t)NODES * NJ * 2);
  const size_t a_cnt = needA;  needA = pad(needA + (size_t)NODES * 4);
  const size_t a_slot = needA; needA = pad(needA + (size_t)NODES * CAP * 4);

  // Tier A2 (exact CSR)
  size_t needA2 = 0;
  const size_t c_xb = needA2;  needA2 = pad(needA2 + (size_t)NODES * DIM * 2);
  const size_t c_wb = needA2;  needA2 = pad(needA2 + (size_t)NREL * DIM * DIM * 2);
  const size_t c_h  = needA2;  needA2 = pad(needA2 + (size_t)NODES * NJ * 2);
  const size_t c_cnt = needA2; needA2 = pad(needA2 + (size_t)NODES * 4);
  const size_t c_rp  = needA2; needA2 = pad(needA2 + ((size_t)NODES + 1) * 4);
  const size_t c_cur = needA2; needA2 = pad(needA2 + (size_t)NODES * 4);
  const size_t c_bs  = needA2; needA2 = pad(needA2 + (size_t)SCAN_BLOCKS * 4);
  const size_t c_sg  = needA2; needA2 = pad(needA2 + (size_t)EDGES * 4);

  char* ws = (char*)d_ws;
  if (needA <= ws_size) {
    u16* xb  = (u16*)(ws + a_xb);
    u16* wb  = (u16*)(ws + a_wb);
    u16* h   = (u16*)(ws + a_h);
    int* cnt = (int*)(ws + a_cnt);
    int* slot = (int*)(ws + a_slot);

    k_prep_pad<<<ZERO_BLKS + CVT_BLKS, 256, 0, stream>>>(x, w, xb, wb, cnt);
    k_scatter_pad<<<EDGE_BLKS, 256, 0, stream>>>(esrc, edst, et, cnt, slot);
    k_gemm<<<GEMM_BLKS, 512, 0, stream>>>(xb, wb, h);
    k_reduce_pad<<<(NODES / 2 * 64 + 255) / 256, 256, 0, stream>>>(h, cnt, slot, bias, out);
  } else if (needA2 <= ws_size) {
    u16* xb  = (u16*)(ws + c_xb);
    u16* wb  = (u16*)(ws + c_wb);
    u16* h   = (u16*)(ws + c_h);
    int* cnt = (int*)(ws + c_cnt);
    int* rp  = (int*)(ws + c_rp);
    int* cur = (int*)(ws + c_cur);
    int* bs  = (int*)(ws + c_bs);
    int* sg  = (int*)(ws + c_sg);

    (void)hipMemsetAsync(cnt, 0, (size_t)NODES * 4, stream);
    k_prep<<<HIST_BLKS + CVT_BLKS, 256, 0, stream>>>(x, w, xb, wb, edst, cnt);
    k_bsum<<<SCAN_BLOCKS, 256, 0, stream>>>(cnt, bs);
    k_bscan<<<1, 256, 0, stream>>>(bs);
    k_scan2<<<SCAN_BLOCKS, 256, 0, stream>>>(cnt, bs, rp, cur);
    k_scatter2<<<EDGE_BLKS, 256, 0, stream>>>(esrc, edst, et, cur, sg);
    k_gemm<<<GEMM_BLKS, 512, 0, stream>>>(xb, wb, h);
    k_reduce_csr<<<(NODES / 2 * 64 + 255) / 256, 256, 0, stream>>>(h, rp, sg, bias, out);
  } else {
    k_init_out<<<12500, 256, 0, stream>>>(out, bias);
    k_naive<<<2048, 256, 0, stream>>>(x, w, esrc, edst, et, out);
  }
}

// Round 13
// 194.568 us; speedup vs baseline: 1.2921x; 1.0344x over previous
//
#include <hip/hip_runtime.h>
#include <hip/hip_bf16.h>
#include <stdint.h>

#define NODES 50000
#define EDGES 800000
#define DIM 256
#define NREL 8
#define NJ (NREL * DIM)  // 2048 combined output cols (r*256+o)
#define CAP 64           // padded-CSR slots per node (Poisson(16): P(deg>=64)~2e-18)

typedef unsigned short u16;
typedef __attribute__((ext_vector_type(8))) __bf16 bf16x8;
typedef __attribute__((ext_vector_type(8))) unsigned short us8;
typedef __attribute__((ext_vector_type(4))) float f32x4;

#define GLOBAL_AS __attribute__((address_space(1)))
#define LDS_AS __attribute__((address_space(3)))

#define CVT_N4 (NODES * DIM / 4 + NREL * DIM * DIM / 4)  // 3,331,072 = 13012*256
#define CVT_BLKS 13012
#define EDGE_BLKS 3125   // 3125*256 == 800000 exactly
#define GEMM_BLKS 3200   // 8 XCD bands x (25 m-tiles x 16 j-tiles)

__device__ __forceinline__ u16 f2bf(float f) {
  uint32_t u = __builtin_bit_cast(uint32_t, f);
  u += 0x7FFFu + ((u >> 16) & 1u);  // RNE; inputs finite
  return (u16)(u >> 16);
}
__device__ __forceinline__ float bf2f(u16 u) {
  uint32_t t = (uint32_t)u << 16;
  return __builtin_bit_cast(float, t);
}

// ---------------- Tier A (padded CSR) ----------------

// Fused: slot-scatter (blocks 0..3124; cnt pre-zeroed by the stream-ordered
// memset) || f32->bf16 convert of x,w (rest).  Safe fusion class (r10/r11):
// both sides LDS-free streaming.  Scatter blocks first: their atomic latency
// starts draining while cvt streams.
__global__ __launch_bounds__(256) void k_prep_pad(
    const float* __restrict__ x, const float* __restrict__ w,
    u16* __restrict__ xb, u16* __restrict__ wb,
    const int* __restrict__ esrc, const int* __restrict__ edst,
    const int* __restrict__ et, int* __restrict__ cnt, int* __restrict__ slot)
{
  const int b = blockIdx.x;
  if (b < EDGE_BLKS) {
    const int e = b * 256 + threadIdx.x;           // exact coverage of EDGES
    const int d = edst[e];
    const int p = atomicAdd(&cnt[d], 1);           // ~16-way avg contention
    if (p < CAP) slot[d * CAP + p] = esrc[e] * NREL + et[e];
    return;
  }
  const int i = (b - EDGE_BLKS) * 256 + threadIdx.x;
  const int n4x = NODES * DIM / 4;
  if (i < n4x) {
    float4 v = ((const float4*)x)[i];
    ushort4 o;
    o.x = f2bf(v.x); o.y = f2bf(v.y); o.z = f2bf(v.z); o.w = f2bf(v.w);
    ((ushort4*)xb)[i] = o;
  } else if (i < CVT_N4) {
    const int j = i - n4x;
    float4 v = ((const float4*)w)[j];
    ushort4 o;
    o.x = f2bf(v.x); o.y = f2bf(v.y); o.z = f2bf(v.z); o.w = f2bf(v.w);
    ((ushort4*)wb)[j] = o;
  }
}

// Dense GEMM h = xb @ wb^T (r9/r11 structure, unchanged).
// BM=256 x BN=128, 512 thr / 8 waves, T1 XCD bands, T4 counted-vmcnt 3-buffer
// pipeline, XOR-swizzled staging, LDS-transpose coalesced epilogue.
__global__ __launch_bounds__(512) void k_gemm(
    const u16* __restrict__ xb, const u16* __restrict__ wb, u16* __restrict__ h)
{
  __shared__ __align__(16) u16 smem[36864];  // 3 x [A 8192 | B 4096] u16

  const int gbid = blockIdx.x;
  const int xcd = gbid & 7;
  const int idx = gbid >> 3;         // 0..399
  const int jg  = idx / 200;         // 0,1
  const int r2  = idx - jg * 200;
  const int m   = xcd * 25 + (r2 >> 3);
  const int mbase = m * 256;
  if (mbase >= NODES) return;
  const int jbase = (jg * 8 + (r2 & 7)) * 128;

  const int tid = threadIdx.x;
  const int lane = tid & 63;
  const int wv = tid >> 6;           // 0..7
  const int wr = wv >> 1, wc = wv & 1;
  const int swz = (lane & 3) ^ ((lane >> 2) & 3) ^ (lane >> 4);  // 16B-chunk idx

  f32x4 acc[4][4];
#pragma unroll
  for (int mm = 0; mm < 4; ++mm)
#pragma unroll
    for (int n = 0; n < 4; ++n) acc[mm][n] = f32x4{0.f, 0.f, 0.f, 0.f};

  const int arow0 = wv * 32;  // this wave stages A rows [arow0, arow0+32)
  const int brow0 = wv * 16;  // and B rows [brow0, brow0+16)

  auto STAGE = [&](int buf, int ks) {
    u16* sa = smem + buf * 12288;
    u16* sb = sa + 8192;
#pragma unroll
    for (int c2 = 0; c2 < 2; ++c2) {
      const int rowb = arow0 + c2 * 16;
      const int row  = rowb + (lane >> 2);
      const int ar = min(mbase + row, NODES - 1);  // clamp last tile
      const u16* ga = xb + ((size_t)ar << 8) + (ks << 5) + (swz << 3);
      __builtin_amdgcn_global_load_lds((const GLOBAL_AS uint32_t*)ga,
                                       (LDS_AS uint32_t*)(sa + rowb * 32), 16, 0, 0);
    }
    const int brow = brow0 + (lane >> 2);
    const u16* gb = wb + ((size_t)(jbase + brow) << 8) + (ks << 5) + (swz << 3);
    __builtin_amdgcn_global_load_lds((const GLOBAL_AS uint32_t*)gb,
                                     (LDS_AS uint32_t*)(sb + brow0 * 32), 16, 0, 0);
  };

  STAGE(0, 0);  // 3 loads in flight
#pragma unroll
  for (int ks = 0; ks < 8; ++ks) {
    if (ks < 7) {
      STAGE((ks + 1) % 3, ks + 1);                       // +3 loads (6 in flight)
      asm volatile("s_waitcnt vmcnt(3)" ::: "memory");   // prev stage landed
    } else {
      asm volatile("s_waitcnt vmcnt(0)" ::: "memory");   // final stage landed
    }
    __builtin_amdgcn_s_barrier();                        // no vmcnt(0) drain here

    const u16* sa = smem + (ks % 3) * 12288;
    const u16* sb = sa + 8192;
    bf16x8 af[4], bfr[4];
#pragma unroll
    for (int mm = 0; mm < 4; ++mm)
      af[mm] = *(const bf16x8*)(sa + (wr * 64 + mm * 16 + (lane & 15)) * 32 + swz * 8);
#pragma unroll
    for (int n = 0; n < 4; ++n)
      bfr[n] = *(const bf16x8*)(sb + (wc * 64 + n * 16 + (lane & 15)) * 32 + swz * 8);
#pragma unroll
    for (int mm = 0; mm < 4; ++mm)
#pragma unroll
      for (int n = 0; n < 4; ++n)
        acc[mm][n] = __builtin_amdgcn_mfma_f32_16x16x32_bf16(af[mm], bfr[n], acc[mm][n], 0, 0, 0);
  }
  __syncthreads();  // all waves done reading bufs before tile overwrite

  // Epilogue: acc -> 256x128 LDS tile, then coalesced 16B stores.
  u16* tile = smem;  // 256x128 u16 = 64KB
#pragma unroll
  for (int mm = 0; mm < 4; ++mm) {
#pragma unroll
    for (int q = 0; q < 4; ++q) {
      const int rt = wr * 64 + mm * 16 + (lane >> 4) * 4 + q;
      const int key = ((rt >> 2) & 3) << 4;
#pragma unroll
      for (int n = 0; n < 4; ++n) {
        const int ct = wc * 64 + n * 16 + (lane & 15);
        tile[rt * 128 + (ct ^ key)] = f2bf(acc[mm][n][q]);
      }
    }
  }
  __syncthreads();
#pragma unroll
  for (int i = 0; i < 8; ++i) {
    const int c = tid + i * 512;
    const int row = c >> 4, chunk = c & 15;
    const int grow = mbase + row;
    if (grow < NODES) {
      const int key = ((row >> 2) & 3) << 4;
      const us8 v = *(const us8*)(tile + row * 128 + ((chunk * 8) ^ key));
      *((us8*)(h + (size_t)grow * NJ + jbase) + chunk) = v;
    }
  }
}

// Two dst nodes per wave (32 lanes x ushort8 = 512B row), padded slots.
// 8 gathers in flight per half-wave (deg~16 = exactly 2 iterations): if the
// r12 4-deep version was latency-bound this doubles MLP.
__global__ __launch_bounds__(256) void k_reduce_pad(
    const u16* __restrict__ h, const int* __restrict__ cnt,
    const int* __restrict__ slot, const float* __restrict__ bias,
    float* __restrict__ out)
{
  const int gw = (int)((blockIdx.x * blockDim.x + threadIdx.x) >> 6);
  const int node = gw * 2 + ((threadIdx.x >> 5) & 1);
  if (node >= NODES) return;
  const int l = threadIdx.x & 31;
  const int lo = node * CAP;
  const int hi = lo + min(cnt[node], CAP);
  const u16* hb = h + l * 8;

  float a[8] = {0.f, 0.f, 0.f, 0.f, 0.f, 0.f, 0.f, 0.f};
  int e = lo;
  for (; e + 8 <= hi; e += 8) {  // 8 x 512B gathers in flight per half-wave
    const us8 v0 = *(const us8*)(hb + ((size_t)slot[e] << 8));
    const us8 v1 = *(const us8*)(hb + ((size_t)slot[e + 1] << 8));
    const us8 v2 = *(const us8*)(hb + ((size_t)slot[e + 2] << 8));
    const us8 v3 = *(const us8*)(hb + ((size_t)slot[e + 3] << 8));
    const us8 v4 = *(const us8*)(hb + ((size_t)slot[e + 4] << 8));
    const us8 v5 = *(const us8*)(hb + ((size_t)slot[e + 5] << 8));
    const us8 v6 = *(const us8*)(hb + ((size_t)slot[e + 6] << 8));
    const us8 v7 = *(const us8*)(hb + ((size_t)slot[e + 7] << 8));
#pragma unroll
    for (int j = 0; j < 8; ++j)
      a[j] += ((bf2f(v0[j]) + bf2f(v1[j])) + (bf2f(v2[j]) + bf2f(v3[j]))) +
              ((bf2f(v4[j]) + bf2f(v5[j])) + (bf2f(v6[j]) + bf2f(v7[j])));
  }
  for (; e + 2 <= hi; e += 2) {
    const us8 v0 = *(const us8*)(hb + ((size_t)slot[e] << 8));
    const us8 v1 = *(const us8*)(hb + ((size_t)slot[e + 1] << 8));
#pragma unroll
    for (int j = 0; j < 8; ++j) a[j] += bf2f(v0[j]) + bf2f(v1[j]);
  }
  if (e < hi) {
    const us8 v = *(const us8*)(hb + ((size_t)slot[e] << 8));
#pragma unroll
    for (int j = 0; j < 8; ++j) a[j] += bf2f(v[j]);
  }
  const float4 b0 = ((const float4*)bias)[l * 2];
  const float4 b1 = ((const float4*)bias)[l * 2 + 1];
  f32x4 o0 = {a[0] + b0.x, a[1] + b0.y, a[2] + b0.z, a[3] + b0.w};
  f32x4 o1 = {a[4] + b1.x, a[5] + b1.y, a[6] + b1.z, a[7] + b1.w};
  f32x4* op = (f32x4*)(out + (size_t)node * DIM) + l * 2;
  __builtin_nontemporal_store(o0, op);
  __builtin_nontemporal_store(o1, op + 1);
}

// ---------------- Tier A2: exact-CSR path (r11) if ws too small for slots ----------------

#define HIST_BLKS 3125
__global__ __launch_bounds__(256) void k_prep(
    const float* __restrict__ x, const float* __restrict__ w,
    u16* __restrict__ xb, u16* __restrict__ wb,
    const int* __restrict__ edst, int* __restrict__ cnt)
{
  const int b = blockIdx.x;
  if (b < HIST_BLKS) {
    const int e = b * 256 + threadIdx.x;
    atomicAdd(&cnt[edst[e]], 1);
    return;
  }
  const int i = (b - HIST_BLKS) * 256 + threadIdx.x;
  const int n4x = NODES * DIM / 4;
  if (i < n4x) {
    float4 v = ((const float4*)x)[i];
    ushort4 o;
    o.x = f2bf(v.x); o.y = f2bf(v.y); o.z = f2bf(v.z); o.w = f2bf(v.w);
    ((ushort4*)xb)[i] = o;
  } else if (i < CVT_N4) {
    const int j = i - n4x;
    float4 v = ((const float4*)w)[j];
    ushort4 o;
    o.x = f2bf(v.x); o.y = f2bf(v.y); o.z = f2bf(v.z); o.w = f2bf(v.w);
    ((ushort4*)wb)[j] = o;
  }
}
#define SCAN_BLOCKS 196
__global__ void k_bsum(const int* __restrict__ cnt, int* __restrict__ bs) {
  int i = blockIdx.x * blockDim.x + threadIdx.x;
  int v = (i < NODES) ? cnt[i] : 0;
#pragma unroll
  for (int o = 32; o; o >>= 1) v += __shfl_down(v, o);
  __shared__ int wsum[4];
  if ((threadIdx.x & 63) == 0) wsum[threadIdx.x >> 6] = v;
  __syncthreads();
  if (threadIdx.x == 0) bs[blockIdx.x] = wsum[0] + wsum[1] + wsum[2] + wsum[3];
}
__global__ void k_bscan(int* __restrict__ bs) {
  __shared__ int tmp[SCAN_BLOCKS];
  int t = threadIdx.x;
  if (t < SCAN_BLOCKS) tmp[t] = bs[t];
  __syncthreads();
  if (t == 0) {
    int s = 0;
    for (int i = 0; i < SCAN_BLOCKS; ++i) { int c = tmp[i]; tmp[i] = s; s += c; }
  }
  __syncthreads();
  if (t < SCAN_BLOCKS) bs[t] = tmp[t];
}
__global__ void k_scan2(const int* __restrict__ cnt, const int* __restrict__ bs,
                        int* __restrict__ row_ptr, int* __restrict__ cur) {
  int t = threadIdx.x;
  int i = blockIdx.x * blockDim.x + t;
  int v = (i < NODES) ? cnt[i] : 0;
  __shared__ int tmp[256];
  tmp[t] = v;
  __syncthreads();
  for (int o = 1; o < 256; o <<= 1) {
    int u = (t >= o) ? tmp[t - o] : 0;
    __syncthreads();
    tmp[t] += u;
    __syncthreads();
  }
  int val = bs[blockIdx.x] + tmp[t] - v;
  if (i <= NODES) row_ptr[i] = val;
  if (i < NODES) cur[i] = val;
}
__global__ __launch_bounds__(256) void k_scatter2(
    const int* __restrict__ esrc, const int* __restrict__ edst,
    const int* __restrict__ et, int* __restrict__ cur, int* __restrict__ sg)
{
  const int e = blockIdx.x * 256 + threadIdx.x;
  const int p = atomicAdd(&cur[edst[e]], 1);
  sg[p] = esrc[e] * NREL + et[e];
}
__global__ __launch_bounds__(256) void k_reduce_csr(
    const u16* __restrict__ h, const int* __restrict__ row_ptr,
    const int* __restrict__ sg, const float* __restrict__ bias,
    float* __restrict__ out)
{
  const int gw = (int)((blockIdx.x * blockDim.x + threadIdx.x) >> 6);
  const int node = gw * 2 + ((threadIdx.x >> 5) & 1);
  if (node >= NODES) return;
  const int l = threadIdx.x & 31;
  const int lo = row_ptr[node], hi = row_ptr[node + 1];
  const u16* hb = h + l * 8;
  float a[8] = {0.f, 0.f, 0.f, 0.f, 0.f, 0.f, 0.f, 0.f};
  int e = lo;
  for (; e + 4 <= hi; e += 4) {
    const us8 v0 = *(const us8*)(hb + ((size_t)sg[e] << 8));
    const us8 v1 = *(const us8*)(hb + ((size_t)sg[e + 1] << 8));
    const us8 v2 = *(const us8*)(hb + ((size_t)sg[e + 2] << 8));
    const us8 v3 = *(const us8*)(hb + ((size_t)sg[e + 3] << 8));
#pragma unroll
    for (int j = 0; j < 8; ++j)
      a[j] += (bf2f(v0[j]) + bf2f(v1[j])) + (bf2f(v2[j]) + bf2f(v3[j]));
  }
  for (; e < hi; ++e) {
    const us8 v = *(const us8*)(hb + ((size_t)sg[e] << 8));
#pragma unroll
    for (int j = 0; j < 8; ++j) a[j] += bf2f(v[j]);
  }
  const float4 b0 = ((const float4*)bias)[l * 2];
  const float4 b1 = ((const float4*)bias)[l * 2 + 1];
  f32x4 o0 = {a[0] + b0.x, a[1] + b0.y, a[2] + b0.z, a[3] + b0.w};
  f32x4 o1 = {a[4] + b1.x, a[5] + b1.y, a[6] + b1.z, a[7] + b1.w};
  f32x4* op = (f32x4*)(out + (size_t)node * DIM) + l * 2;
  __builtin_nontemporal_store(o0, op);
  __builtin_nontemporal_store(o1, op + 1);
}

// ---------------- Tier C fallback ----------------

__global__ void k_init_out(float* __restrict__ out, const float* __restrict__ bias) {
  int i = blockIdx.x * blockDim.x + threadIdx.x;
  ((float4*)out)[i] = ((const float4*)bias)[i & 63];
}
__global__ void k_naive(const float* __restrict__ x, const float* __restrict__ w,
                        const int* __restrict__ esrc, const int* __restrict__ edst,
                        const int* __restrict__ et, float* __restrict__ out)
{
  const int lane = threadIdx.x & 63;
  int gw = (blockIdx.x * blockDim.x + threadIdx.x) >> 6;
  const int nw = (gridDim.x * blockDim.x) >> 6;
  for (int e = gw; e < EDGES; e += nw) {
    const int s = esrc[e], d = edst[e], r = et[e];
    const float* xr = x + (size_t)s * DIM;
    const float* wr0 = w + (size_t)r * DIM * DIM;
    float a[4] = {0.f, 0.f, 0.f, 0.f};
    for (int i = 0; i < DIM; ++i) {
      const float xv = xr[i];
#pragma unroll
      for (int c = 0; c < 4; ++c) a[c] += xv * wr0[(size_t)(lane + c * 64) * DIM + i];
    }
#pragma unroll
    for (int c = 0; c < 4; ++c) atomicAdd(&out[(size_t)d * DIM + lane + c * 64], a[c]);
  }
}

extern "C" void kernel_launch(void* const* d_in, const int* in_sizes, int n_in,
                              void* d_out, int out_size, void* d_ws, size_t ws_size,
                              hipStream_t stream) {
  const float* x    = (const float*)d_in[0];
  const float* w    = (const float*)d_in[1];
  const float* bias = (const float*)d_in[2];
  const int* eidx   = (const int*)d_in[3];
  const int* et     = (const int*)d_in[4];
  const int* esrc = eidx;
  const int* edst = eidx + EDGES;
  float* out = (float*)d_out;

  auto pad = [](size_t v) { return (v + 255) & ~(size_t)255; };

  // Tier A (padded CSR)
  size_t needA = 0;
  const size_t a_xb = needA;   needA = pad(needA + (size_t)NODES * DIM * 2);
  const size_t a_wb = needA;   needA = pad(needA + (size_t)NREL * DIM * DIM * 2);
  const size_t a_h  = needA;   needA = pad(needA + (size_t)NODES * NJ * 2);
  const size_t a_cnt = needA;  needA = pad(needA + (size_t)NODES * 4);
  const size_t a_slot = needA; needA = pad(needA + (size_t)NODES * CAP * 4);

  // Tier A2 (exact CSR)
  size_t needA2 = 0;
  const size_t c_xb = needA2;  needA2 = pad(needA2 + (size_t)NODES * DIM * 2);
  const size_t c_wb = needA2;  needA2 = pad(needA2 + (size_t)NREL * DIM * DIM * 2);
  const size_t c_h  = needA2;  needA2 = pad(needA2 + (size_t)NODES * NJ * 2);
  const size_t c_cnt = needA2; needA2 = pad(needA2 + (size_t)NODES * 4);
  const size_t c_rp  = needA2; needA2 = pad(needA2 + ((size_t)NODES + 1) * 4);
  const size_t c_cur = needA2; needA2 = pad(needA2 + (size_t)NODES * 4);
  const size_t c_bs  = needA2; needA2 = pad(needA2 + (size_t)SCAN_BLOCKS * 4);
  const size_t c_sg  = needA2; needA2 = pad(needA2 + (size_t)EDGES * 4);

  char* ws = (char*)d_ws;
  if (needA <= ws_size) {
    u16* xb  = (u16*)(ws + a_xb);
    u16* wb  = (u16*)(ws + a_wb);
    u16* h   = (u16*)(ws + a_h);
    int* cnt = (int*)(ws + a_cnt);
    int* slot = (int*)(ws + a_slot);

    (void)hipMemsetAsync(cnt, 0, (size_t)NODES * 4, stream);
    k_prep_pad<<<EDGE_BLKS + CVT_BLKS, 256, 0, stream>>>(x, w, xb, wb, esrc, edst, et, cnt, slot);
    k_gemm<<<GEMM_BLKS, 512, 0, stream>>>(xb, wb, h);
    k_reduce_pad<<<(NODES / 2 * 64 + 255) / 256, 256, 0, stream>>>(h, cnt, slot, bias, out);
  } else if (needA2 <= ws_size) {
    u16* xb  = (u16*)(ws + c_xb);
    u16* wb  = (u16*)(ws + c_wb);
    u16* h   = (u16*)(ws + c_h);
    int* cnt = (int*)(ws + c_cnt);
    int* rp  = (int*)(ws + c_rp);
    int* cur = (int*)(ws + c_cur);
    int* bs  = (int*)(ws + c_bs);
    int* sg  = (int*)(ws + c_sg);

    (void)hipMemsetAsync(cnt, 0, (size_t)NODES * 4, stream);
    k_prep<<<HIST_BLKS + CVT_BLKS, 256, 0, stream>>>(x, w, xb, wb, edst, cnt);
    k_bsum<<<SCAN_BLOCKS, 256, 0, stream>>>(cnt, bs);
    k_bscan<<<1, 256, 0, stream>>>(bs);
    k_scan2<<<SCAN_BLOCKS, 256, 0, stream>>>(cnt, bs, rp, cur);
    k_scatter2<<<EDGE_BLKS, 256, 0, stream>>>(esrc, edst, et, cur, sg);
    k_gemm<<<GEMM_BLKS, 512, 0, stream>>>(xb, wb, h);
    k_reduce_csr<<<(NODES / 2 * 64 + 255) / 256, 256, 0, stream>>>(h, rp, sg, bias, out);
  } else {
    k_init_out<<<12500, 256, 0, stream>>>(out, bias);
    k_naive<<<2048, 256, 0, stream>>>(x, w, esrc, edst, et, out);
  }
}